// Round 4
// baseline (425.802 us; speedup 1.0000x reference)
//
#include <hip/hip_runtime.h>

#define BATCH 64
#define SEQ 729
#define DIM 64
#define NT 12      // ceil(729/64)
#define STRB 72    // bf16 LDS row stride (Ks/Vs/Qs)
#define STRW 68    // dword LDS row stride (mask/P fp32 tile): 16B-aligned rows

typedef __attribute__((ext_vector_type(8))) short bf16x8;
typedef __attribute__((ext_vector_type(4))) float f32x4;
// 4B-aligned vector views for the 729-strided global rows
typedef int   i32x4a __attribute__((ext_vector_type(4), aligned(4)));
typedef float f32x4a __attribute__((ext_vector_type(4), aligned(4)));

__device__ __forceinline__ unsigned short f2bf(float f) {
    unsigned int u = __float_as_uint(f);
    u += 0x7fffu + ((u >> 16) & 1u);   // round-to-nearest-even
    return (unsigned short)(u >> 16);
}

__device__ __forceinline__ unsigned long long pack4bf(float a, float b, float c, float d) {
    return (unsigned long long)f2bf(a)
         | ((unsigned long long)f2bf(b) << 16)
         | ((unsigned long long)f2bf(c) << 32)
         | ((unsigned long long)f2bf(d) << 48);
}

// tanh(x) = 1 - 2/(exp2(2x*log2e)+1)
__device__ __forceinline__ float fast_tanh(float x) {
    float e = __builtin_amdgcn_exp2f(x * 2.88539008177792681f);
    return 1.0f - 2.0f * __builtin_amdgcn_rcpf(e + 1.0f);
}

// launch_bounds(256,3): VGPR cap ~168. Persistent regs ~104 (K/M 2-deep named
// scalars + V 1-deep + frags + oacc); peak ~150 -> no spill expected.
// LDS 45KB limits to 3 blocks/CU (grid = 768 = exactly 3/CU).
__global__ __launch_bounds__(256, 3) void attn_kernel(
    const float* __restrict__ Qg, const float* __restrict__ Kg,
    const float* __restrict__ Vg, const int* __restrict__ Mg,
    float* __restrict__ Og, float* __restrict__ Ag)
{
    __shared__ unsigned short Ks[64 * STRB];  // [k][d] bf16
    __shared__ unsigned short Vs[64 * STRB];  // [d][k] bf16 (transposed)
    __shared__ unsigned short Qs[64 * STRB];  // Q bf16, then P bf16 (wave-private rows)
    __shared__ float Pf[64 * STRW];           // mask int, then P fp32 (wave-private rows)
    int* Mint = (int*)Pf;

    const int tid = threadIdx.x;
    const int q0  = blockIdx.x * 64;
    const int b   = blockIdx.y;

    const float* Qb = Qg + (size_t)b * SEQ * DIM;
    const float* Kb = Kg + (size_t)b * SEQ * DIM;
    const float* Vb = Vg + (size_t)b * SEQ * DIM;
    const int*   Mb = Mg + (size_t)b * SEQ * SEQ;
    float* Ob = Og + (size_t)b * SEQ * DIM;
    float* Ab = Ag + (size_t)b * SEQ * SEQ;

    const int lane = tid & 63;
    const int quad = lane >> 4;
    const int l15  = lane & 15;
    const int qrow = (tid >> 6) * 16;      // wave's q-strip base (local)

    // block-cooperative staging geometry: 16 consecutive threads cover one
    // row's 64 cols -> 256B contiguous segments, float4 per lane
    const int rr = tid >> 4;               // row group 0..15 (+16*i)
    const int cc = (tid & 15) * 4;         // col (floats)
    const int vd0 = (tid & 15) * 4;        // V: dims
    const int vk0 = (tid >> 4) * 4;        // V: k rows
    // wave-private mask/P row-major geometry: 16 lanes cover one row's 64 cols
    const int prow = qrow + (lane >> 4);   // + 4*i -> rows qrow..qrow+15
    const int pcol = (lane & 15) * 4;

    // 2-deep prefetch state as INDIVIDUALLY NAMED variables (rounds 1-3 lesson:
    // arrays / array-reference params get memory-backed -> scratch disaster)
    float4 krA0, krA1, krA2, krA3;
    float4 krB0, krB1, krB2, krB3;
    float4 vr0, vr1, vr2, vr3;             // V: 1-deep (in-order vmcnt gives it
                                           // a full phase of lead anyway)
    i32x4a mrA0, mrA1, mrA2, mrA3;
    i32x4a mrB0, mrB1, mrB2, mrB3;

#define LOAD_K1(k0n, KX, i) { \
    int gk_ = (k0n) + rr + 16 * (i); \
    KX = (gk_ < SEQ) ? *(const float4*)(Kb + gk_ * DIM + cc) : float4{0,0,0,0}; }
#define LOAD_K(k0n, K0,K1,K2,K3) { \
    LOAD_K1(k0n, K0, 0) LOAD_K1(k0n, K1, 1) LOAD_K1(k0n, K2, 2) LOAD_K1(k0n, K3, 3) }

#define LOAD_V1(k0n, VX, i) { \
    int gk_ = (k0n) + vk0 + (i); \
    VX = (gk_ < SEQ) ? *(const float4*)(Vb + gk_ * DIM + vd0) : float4{0,0,0,0}; }
#define LOAD_V(k0n) { \
    LOAD_V1(k0n, vr0, 0) LOAD_V1(k0n, vr1, 1) LOAD_V1(k0n, vr2, 2) LOAD_V1(k0n, vr3, 3) }

#define LOAD_M1(k0n, MX, i) { \
    int gq_ = q0 + prow + 4 * (i); \
    int gk_ = (k0n) + pcol; \
    if (gq_ < SEQ && gk_ + 3 < SEQ) { \
        MX = *(const i32x4a*)(Mb + (size_t)gq_ * SEQ + gk_); \
    } else if (gq_ < SEQ) { \
        i32x4a t_; \
        for (int e_ = 0; e_ < 4; ++e_) \
            t_[e_] = (gk_ + e_ < SEQ) ? Mb[(size_t)gq_ * SEQ + gk_ + e_] : 0; \
        MX = t_; \
    } else { MX = i32x4a{0,0,0,0}; } }
#define LOAD_M(k0n, M0,M1,M2,M3) { \
    LOAD_M1(k0n, M0, 0) LOAD_M1(k0n, M1, 1) LOAD_M1(k0n, M2, 2) LOAD_M1(k0n, M3, 3) }

#define DRAIN_M(M0,M1,M2,M3) { \
    *(i32x4a*)&Mint[(prow +  0) * STRW + pcol] = M0; \
    *(i32x4a*)&Mint[(prow +  4) * STRW + pcol] = M1; \
    *(i32x4a*)&Mint[(prow +  8) * STRW + pcol] = M2; \
    *(i32x4a*)&Mint[(prow + 12) * STRW + pcol] = M3; }

#define DRAIN_K(K0,K1,K2,K3) { \
    *(unsigned long long*)&Ks[(rr +  0) * STRB + cc] = pack4bf(K0.x, K0.y, K0.z, K0.w); \
    *(unsigned long long*)&Ks[(rr + 16) * STRB + cc] = pack4bf(K1.x, K1.y, K1.z, K1.w); \
    *(unsigned long long*)&Ks[(rr + 32) * STRB + cc] = pack4bf(K2.x, K2.y, K2.z, K2.w); \
    *(unsigned long long*)&Ks[(rr + 48) * STRB + cc] = pack4bf(K3.x, K3.y, K3.z, K3.w); }

#define DRAIN_V() { \
    *(unsigned long long*)&Vs[(vd0 + 0) * STRB + vk0] = pack4bf(vr0.x, vr1.x, vr2.x, vr3.x); \
    *(unsigned long long*)&Vs[(vd0 + 1) * STRB + vk0] = pack4bf(vr0.y, vr1.y, vr2.y, vr3.y); \
    *(unsigned long long*)&Vs[(vd0 + 2) * STRB + vk0] = pack4bf(vr0.z, vr1.z, vr2.z, vr3.z); \
    *(unsigned long long*)&Vs[(vd0 + 3) * STRB + vk0] = pack4bf(vr0.w, vr1.w, vr2.w, vr3.w); }

/* one k-tile phase; K/M set passed as named variables (textual) */
#define STEP(kt, K0,K1,K2,K3, M0,M1,M2,M3) { \
    const int k0_ = (kt) * 64; \
    __syncthreads(); /* prev tile's Ks/Vs readers done */ \
    DRAIN_M(M0,M1,M2,M3); /* waits only this set's loads (oldest in queue) */ \
    DRAIN_K(K0,K1,K2,K3); \
    DRAIN_V(); \
    __syncthreads(); /* staging visible */ \
    if ((kt) + 1 < NT) { LOAD_V(k0_ + 64) }                    /* 1-deep */ \
    if ((kt) + 2 < NT) { LOAD_K(k0_ + 128, K0,K1,K2,K3) \
                         LOAD_M(k0_ + 128, M0,M1,M2,M3) }      /* 2-deep */ \
    f32x4 sacc0, sacc1, sacc2, sacc3; \
    _Pragma("unroll") \
    for (int n_ = 0; n_ < 4; ++n_) { \
        bf16x8 bk0 = *(const bf16x8*)&Ks[(n_ * 16 + l15) * STRB + quad * 8]; \
        bf16x8 bk1 = *(const bf16x8*)&Ks[(n_ * 16 + l15) * STRB + 32 + quad * 8]; \
        f32x4 c_; c_[0]=0.f; c_[1]=0.f; c_[2]=0.f; c_[3]=0.f; \
        c_ = __builtin_amdgcn_mfma_f32_16x16x32_bf16(aq0, bk0, c_, 0, 0, 0); \
        c_ = __builtin_amdgcn_mfma_f32_16x16x32_bf16(aq1, bk1, c_, 0, 0, 0); \
        if (n_ == 0) sacc0 = c_; else if (n_ == 1) sacc1 = c_; \
        else if (n_ == 2) sacc2 = c_; else sacc3 = c_; \
    } \
    _Pragma("unroll") \
    for (int n_ = 0; n_ < 4; ++n_) { \
        f32x4 sv_ = (n_ == 0) ? sacc0 : (n_ == 1) ? sacc1 : (n_ == 2) ? sacc2 : sacc3; \
        int col_ = n_ * 16 + l15; \
        int gk_  = k0_ + col_; \
        _Pragma("unroll") \
        for (int r_ = 0; r_ < 4; ++r_) { \
            int qloc_ = qrow + quad * 4 + r_; \
            int gq_ = q0 + qloc_; \
            int m_ = Mint[qloc_ * STRW + col_]; \
            float s_ = sv_[r_] * 0.125f; /* 1/sqrt(64) */ \
            bool msk_ = (m_ == 0); \
            float p_ = fast_tanh(msk_ ? -1e9f : s_); \
            if (msk_) p_ = -1.0f; \
            if (gq_ == gk_) p_ = 0.0f; /* ignore_diag */ \
            if (gq_ >= SEQ || gk_ >= SEQ) p_ = 0.0f; /* padding */ \
            Pf[qloc_ * STRW + col_] = p_; /* in-place over mask */ \
            Qs[qloc_ * STRB + col_] = f2bf(p_); \
        } \
    } \
    _Pragma("unroll") \
    for (int i_ = 0; i_ < 4; ++i_) { \
        int row_ = prow + 4 * i_; \
        int gq_  = q0 + row_; \
        int gk_  = k0_ + pcol; \
        f32x4 pv_ = *(const f32x4*)&Pf[row_ * STRW + pcol]; \
        if (gq_ < SEQ) { \
            if (gk_ + 3 < SEQ) { \
                *(f32x4a*)(Ab + (size_t)gq_ * SEQ + gk_) = pv_; \
            } else { \
                for (int e_ = 0; e_ < 4; ++e_) \
                    if (gk_ + e_ < SEQ) Ab[(size_t)gq_ * SEQ + gk_ + e_] = pv_[e_]; \
            } \
        } \
    } \
    { \
        const bf16x8 ap0 = *(const bf16x8*)&Qs[(qrow + l15) * STRB + quad * 8]; \
        const bf16x8 ap1 = *(const bf16x8*)&Qs[(qrow + l15) * STRB + 32 + quad * 8]; \
        _Pragma("unroll") \
        for (int dt_ = 0; dt_ < 4; ++dt_) { \
            bf16x8 bv0 = *(const bf16x8*)&Vs[(dt_ * 16 + l15) * STRB + quad * 8]; \
            bf16x8 bv1 = *(const bf16x8*)&Vs[(dt_ * 16 + l15) * STRB + 32 + quad * 8]; \
            oacc[dt_] = __builtin_amdgcn_mfma_f32_16x16x32_bf16(ap0, bv0, oacc[dt_], 0, 0, 0); \
            oacc[dt_] = __builtin_amdgcn_mfma_f32_16x16x32_bf16(ap1, bv1, oacc[dt_], 0, 0, 0); \
        } \
    } }

    // ---- stage Q tile (256B-coalesced float4 loads) ----
    #pragma unroll
    for (int i = 0; i < 4; ++i) {
        int gq = q0 + rr + 16 * i;
        float4 x = (gq < SEQ) ? *(const float4*)(Qb + gq * DIM + cc)
                              : float4{0, 0, 0, 0};
        *(unsigned long long*)&Qs[(rr + 16 * i) * STRB + cc] = pack4bf(x.x, x.y, x.z, x.w);
    }
    __syncthreads();

    // hoist loop-invariant Q fragments; Qs becomes the P bf16 buffer
    const bf16x8 aq0 = *(const bf16x8*)&Qs[(qrow + l15) * STRB + quad * 8];
    const bf16x8 aq1 = *(const bf16x8*)&Qs[(qrow + l15) * STRB + 32 + quad * 8];

    // prologue: tile0 (A) + V(0) first, then tile1 (B) stays younger in the
    // in-order vmcnt queue -> drain(0)'s wait leaves tile1 in flight
    LOAD_K(0, krA0,krA1,krA2,krA3)
    LOAD_M(0, mrA0,mrA1,mrA2,mrA3)
    LOAD_V(0)
    LOAD_K(64, krB0,krB1,krB2,krB3)
    LOAD_M(64, mrB0,mrB1,mrB2,mrB3)

    f32x4 oacc[4];
    #pragma unroll
    for (int dt = 0; dt < 4; ++dt) {
        oacc[dt][0]=0.f; oacc[dt][1]=0.f; oacc[dt][2]=0.f; oacc[dt][3]=0.f;
    }

    for (int kt = 0; kt < NT; kt += 2) {
        STEP(kt,     krA0,krA1,krA2,krA3, mrA0,mrA1,mrA2,mrA3)
        STEP(kt + 1, krB0,krB1,krB2,krB3, mrB0,mrB1,mrB2,mrB3)
    }

    // ---- epilogue: stage out tile in Pf (wave-private), write float4 ----
    #pragma unroll
    for (int dt = 0; dt < 4; ++dt)
        #pragma unroll
        for (int r = 0; r < 4; ++r)
            Pf[(qrow + quad * 4 + r) * STRW + dt * 16 + l15] = oacc[dt][r];
    #pragma unroll
    for (int i = 0; i < 4; ++i) {
        int row = prow + 4 * i;
        int gq  = q0 + row;
        f32x4 ov = *(const f32x4*)&Pf[row * STRW + pcol];
        if (gq < SEQ) *(f32x4*)(Ob + (size_t)gq * DIM + pcol) = ov;  // 16B-aligned
    }
}

extern "C" void kernel_launch(void* const* d_in, const int* in_sizes, int n_in,
                              void* d_out, int out_size, void* d_ws, size_t ws_size,
                              hipStream_t stream) {
    const float* Q = (const float*)d_in[0];
    const float* K = (const float*)d_in[1];
    const float* V = (const float*)d_in[2];
    const int*   M = (const int*)d_in[3];
    float* Out  = (float*)d_out;
    float* Attn = Out + (size_t)BATCH * SEQ * DIM;   // tuple order: (out, attention)
    dim3 grid(NT, BATCH);
    attn_kernel<<<grid, 256, 0, stream>>>(Q, K, V, M, Out, Attn);
}

// Round 5
// 326.648 us; speedup vs baseline: 1.3036x; 1.3036x over previous
//
#include <hip/hip_runtime.h>

#define BATCH 64
#define SEQ 729
#define DIM 64
#define NT 12      // ceil(729/64)
#define STRB 72    // bf16 LDS row stride (Ks/Vs/Qs)
#define STRW 68    // dword LDS row stride (mask/P fp32 tile): 16B-aligned rows

typedef __attribute__((ext_vector_type(8))) short bf16x8;
typedef __attribute__((ext_vector_type(4))) float f32x4;
// 4B-aligned vector views for the 729-strided global rows (gfx950 supports
// unaligned global dwordx4; rows are only dword-aligned since 729*4 % 16 != 0)
typedef int   i32x4a __attribute__((ext_vector_type(4), aligned(4)));
typedef float f32x4a __attribute__((ext_vector_type(4), aligned(4)));

__device__ __forceinline__ unsigned short f2bf(float f) {
    unsigned int u = __float_as_uint(f);
    u += 0x7fffu + ((u >> 16) & 1u);   // round-to-nearest-even
    return (unsigned short)(u >> 16);
}

__device__ __forceinline__ unsigned long long pack4bf(float a, float b, float c, float d) {
    return (unsigned long long)f2bf(a)
         | ((unsigned long long)f2bf(b) << 16)
         | ((unsigned long long)f2bf(c) << 32)
         | ((unsigned long long)f2bf(d) << 48);
}

// tanh(x) = 1 - 2/(exp2(2x*log2e)+1)
__device__ __forceinline__ float fast_tanh(float x) {
    float e = __builtin_amdgcn_exp2f(x * 2.88539008177792681f);
    return 1.0f - 2.0f * __builtin_amdgcn_rcpf(e + 1.0f);
}

// Raw barrier WITHOUT the __syncthreads() vmcnt(0) drain: only LDS ops are
// fenced (release/acquire for Ks/Vs). Prefetch loads + attn stores stay in
// flight across phases; the compiler's own COUNTED vmcnt at the register
// drain waits exactly the loads it needs. sched_barrier(0) per rule #18.
#define BAR() do { \
    asm volatile("s_waitcnt lgkmcnt(0)" ::: "memory"); \
    __builtin_amdgcn_s_barrier(); \
    __builtin_amdgcn_sched_barrier(0); \
} while (0)

__global__ __launch_bounds__(256, 3) void attn_kernel(
    const float* __restrict__ Qg, const float* __restrict__ Kg,
    const float* __restrict__ Vg, const int* __restrict__ Mg,
    float* __restrict__ Og, float* __restrict__ Ag)
{
    __shared__ unsigned short Ks[64 * STRB];  // [k][d] bf16
    __shared__ unsigned short Vs[64 * STRB];  // [d][k] bf16 (transposed)
    __shared__ unsigned short Qs[64 * STRB];  // Q bf16, then P bf16 (wave-private rows)
    __shared__ float Pf[64 * STRW];           // mask int, then P fp32 (wave-private rows)
    int* Mint = (int*)Pf;

    const int tid = threadIdx.x;
    const int q0  = blockIdx.x * 64;
    const int b   = blockIdx.y;

    const float* Qb = Qg + (size_t)b * SEQ * DIM;
    const float* Kb = Kg + (size_t)b * SEQ * DIM;
    const float* Vb = Vg + (size_t)b * SEQ * DIM;
    const int*   Mb = Mg + (size_t)b * SEQ * SEQ;
    float* Ob = Og + (size_t)b * SEQ * DIM;
    float* Ab = Ag + (size_t)b * SEQ * SEQ;

    const int lane = tid & 63;
    const int quad = lane >> 4;
    const int l15  = lane & 15;
    const int qrow = (tid >> 6) * 16;      // wave's q-strip base (local)

    // block-cooperative staging geometry: 16 consecutive threads cover one
    // row's 64 cols -> 256B contiguous segments, float4 per lane
    const int rr = tid >> 4;               // row group 0..15 (+16*i)
    const int cc = (tid & 15) * 4;         // col (floats)
    // V staging (row-2 scheme, already 256B-coalesced)
    const int vd0 = (tid & 15) * 4;        // dims
    const int vk0 = (tid >> 4) * 4;        // k rows
    // wave-private mask/P row-major geometry: 16 lanes cover one row's 64 cols
    const int prow = qrow + (lane >> 4);   // + 4*i -> rows qrow..qrow+15
    const int pcol = (lane & 15) * 4;

    float4 kr[4], vr[4];
    i32x4a mr[4];

    auto load_k = [&](int k0n) {
        #pragma unroll
        for (int i = 0; i < 4; ++i) {
            int gk = k0n + rr + 16 * i;
            kr[i] = (gk < SEQ) ? *(const float4*)(Kb + gk * DIM + cc)
                               : float4{0, 0, 0, 0};
        }
    };
    auto load_v = [&](int k0n) {
        #pragma unroll
        for (int i = 0; i < 4; ++i) {
            int gk = k0n + vk0 + i;
            vr[i] = (gk < SEQ) ? *(const float4*)(Vb + gk * DIM + vd0)
                               : float4{0, 0, 0, 0};
        }
    };
    auto load_mask = [&](int k0n) {
        #pragma unroll
        for (int i = 0; i < 4; ++i) {
            int gq = q0 + prow + 4 * i;
            int gk = k0n + pcol;
            if (gq < SEQ && gk + 3 < SEQ) {
                mr[i] = *(const i32x4a*)(Mb + (size_t)gq * SEQ + gk);
            } else if (gq < SEQ) {
                i32x4a t;
                #pragma unroll
                for (int e = 0; e < 4; ++e)
                    t[e] = (gk + e < SEQ) ? Mb[(size_t)gq * SEQ + gk + e] : 0;
                mr[i] = t;
            } else {
                mr[i] = i32x4a{0, 0, 0, 0};
            }
        }
    };
    auto drain_mask = [&]() {   // wave-private rows -> no barrier needed
        #pragma unroll
        for (int i = 0; i < 4; ++i)
            *(i32x4a*)&Mint[(prow + 4 * i) * STRW + pcol] = mr[i];
    };
    auto drain_kv = [&]() {
        #pragma unroll
        for (int i = 0; i < 4; ++i)
            *(unsigned long long*)&Ks[(rr + 16 * i) * STRB + cc] =
                pack4bf(kr[i].x, kr[i].y, kr[i].z, kr[i].w);
        #pragma unroll
        for (int j = 0; j < 4; ++j) {
            float v0 = j==0?vr[0].x:j==1?vr[0].y:j==2?vr[0].z:vr[0].w;
            float v1 = j==0?vr[1].x:j==1?vr[1].y:j==2?vr[1].z:vr[1].w;
            float v2 = j==0?vr[2].x:j==1?vr[2].y:j==2?vr[2].z:vr[2].w;
            float v3 = j==0?vr[3].x:j==1?vr[3].y:j==2?vr[3].z:vr[3].w;
            *(unsigned long long*)&Vs[(vd0 + j) * STRB + vk0] = pack4bf(v0, v1, v2, v3);
        }
    };

    // ---- stage Q tile (256B-coalesced float4 loads) ----
    #pragma unroll
    for (int i = 0; i < 4; ++i) {
        int gq = q0 + rr + 16 * i;
        float4 x = (gq < SEQ) ? *(const float4*)(Qb + gq * DIM + cc)
                              : float4{0, 0, 0, 0};
        *(unsigned long long*)&Qs[(rr + 16 * i) * STRB + cc] = pack4bf(x.x, x.y, x.z, x.w);
    }
    BAR();   // release Qs to all waves (lgkmcnt only; no vmcnt drain)

    // hoist loop-invariant Q fragments; Qs becomes the P bf16 buffer
    const bf16x8 aq0 = *(const bf16x8*)&Qs[(qrow + l15) * STRB + quad * 8];
    const bf16x8 aq1 = *(const bf16x8*)&Qs[(qrow + l15) * STRB + 32 + quad * 8];

    // preload tile 0 into regs
    load_k(0); load_v(0); load_mask(0);

    f32x4 oacc[4];
    #pragma unroll
    for (int dt = 0; dt < 4; ++dt) {
        oacc[dt][0]=0.f; oacc[dt][1]=0.f; oacc[dt][2]=0.f; oacc[dt][3]=0.f;
    }

    for (int kt = 0; kt < NT; ++kt) {
        const int k0 = kt * 64;

        BAR();                      // prev tile's Ks/Vs readers done (no vmcnt!)
        drain_mask();               // compiler emits COUNTED vmcnt here: waits
        drain_kv();                 // only this tile's loads, stores stay in flight
        BAR();                      // Ks/Vs staging visible (lgkmcnt release)

        // prefetch tile kt+1 into regs (stays in flight across the barriers)
        if (kt + 1 < NT) {
            load_k(k0 + 64); load_v(k0 + 64); load_mask(k0 + 64);
        }

        // ---- QK^T ----
        f32x4 sacc[4];
        #pragma unroll
        for (int nt2 = 0; nt2 < 4; ++nt2) {
            bf16x8 bk0 = *(const bf16x8*)&Ks[(nt2 * 16 + l15) * STRB + quad * 8];
            bf16x8 bk1 = *(const bf16x8*)&Ks[(nt2 * 16 + l15) * STRB + 32 + quad * 8];
            f32x4 c; c[0]=0.f; c[1]=0.f; c[2]=0.f; c[3]=0.f;
            c = __builtin_amdgcn_mfma_f32_16x16x32_bf16(aq0, bk0, c, 0, 0, 0);
            c = __builtin_amdgcn_mfma_f32_16x16x32_bf16(aq1, bk1, c, 0, 0, 0);
            sacc[nt2] = c;
        }

        // ---- scale, mask (from LDS), tanh, zero-diag; write P fp32+bf16 ----
        #pragma unroll
        for (int nt2 = 0; nt2 < 4; ++nt2) {
            int col = nt2 * 16 + l15;
            int gk  = k0 + col;
            #pragma unroll
            for (int r = 0; r < 4; ++r) {
                int qloc = qrow + quad * 4 + r;
                int gq = q0 + qloc;
                int m = Mint[qloc * STRW + col];
                float sv = sacc[nt2][r] * 0.125f;       // 1/sqrt(64)
                bool msk = (m == 0);
                float p = fast_tanh(msk ? -1e9f : sv);
                if (msk) p = -1.0f;
                if (gq == gk) p = 0.0f;                 // ignore_diag
                if (gq >= SEQ || gk >= SEQ) p = 0.0f;   // padding
                Pf[qloc * STRW + col] = p;              // in-place over mask
                Qs[qloc * STRB + col] = f2bf(p);
            }
        }

        // ---- attention write-out: wave-private rows, row-contiguous float4 ----
        #pragma unroll
        for (int i = 0; i < 4; ++i) {
            int row = prow + 4 * i;
            int gq  = q0 + row;
            int gk  = k0 + pcol;
            f32x4 pv = *(const f32x4*)&Pf[row * STRW + pcol];
            if (gq < SEQ) {
                if (gk + 3 < SEQ) {
                    *(f32x4a*)(Ab + (size_t)gq * SEQ + gk) = pv;
                } else {
                    #pragma unroll
                    for (int e = 0; e < 4; ++e)
                        if (gk + e < SEQ) Ab[(size_t)gq * SEQ + gk + e] = pv[e];
                }
            }
        }

        // ---- PV ----
        const bf16x8 ap0 = *(const bf16x8*)&Qs[(qrow + l15) * STRB + quad * 8];
        const bf16x8 ap1 = *(const bf16x8*)&Qs[(qrow + l15) * STRB + 32 + quad * 8];
        #pragma unroll
        for (int dt = 0; dt < 4; ++dt) {
            bf16x8 bv0 = *(const bf16x8*)&Vs[(dt * 16 + l15) * STRB + quad * 8];
            bf16x8 bv1 = *(const bf16x8*)&Vs[(dt * 16 + l15) * STRB + 32 + quad * 8];
            oacc[dt] = __builtin_amdgcn_mfma_f32_16x16x32_bf16(ap0, bv0, oacc[dt], 0, 0, 0);
            oacc[dt] = __builtin_amdgcn_mfma_f32_16x16x32_bf16(ap1, bv1, oacc[dt], 0, 0, 0);
        }
    }

    // ---- epilogue: stage out tile in Pf (wave-private), write float4 ----
    #pragma unroll
    for (int dt = 0; dt < 4; ++dt)
        #pragma unroll
        for (int r = 0; r < 4; ++r)
            Pf[(qrow + quad * 4 + r) * STRW + dt * 16 + l15] = oacc[dt][r];
    #pragma unroll
    for (int i = 0; i < 4; ++i) {
        int row = prow + 4 * i;
        int gq  = q0 + row;
        f32x4 ov = *(const f32x4*)&Pf[row * STRW + pcol];
        if (gq < SEQ) *(f32x4*)(Ob + (size_t)gq * DIM + pcol) = ov;  // 16B-aligned
    }
}

extern "C" void kernel_launch(void* const* d_in, const int* in_sizes, int n_in,
                              void* d_out, int out_size, void* d_ws, size_t ws_size,
                              hipStream_t stream) {
    const float* Q = (const float*)d_in[0];
    const float* K = (const float*)d_in[1];
    const float* V = (const float*)d_in[2];
    const int*   M = (const int*)d_in[3];
    float* Out  = (float*)d_out;
    float* Attn = Out + (size_t)BATCH * SEQ * DIM;   // tuple order: (out, attention)
    dim3 grid(NT, BATCH);
    attn_kernel<<<grid, 256, 0, stream>>>(Q, K, V, M, Out, Attn);
}